// Round 6
// baseline (45.191 us; speedup 1.0000x reference)
//
#include <hip/hip_runtime.h>

// out[b,s,:] = W[:, text[b,s]] + bias + pe[s,:]
// text: int32 [B,S]; W: f32 [D, VOCAB]; bias: f32 [D]; pe: f32 [MAX_LEN, D]
//
// Round 6: keep round-5 binning (proven); rebuild gather as a pipelined
// multi-vocab-tile sweep. Each block: one 32-row d-tile, 8 consecutive
// 128-wide vocab tiles, register->LDS double buffer, one barrier per tile.
// Grid = 1024 blocks = exactly 4 resident blocks/CU (33 KB LDS each).

#define VOCAB  32000
#define DMODEL 1024
#define S_LEN  2048
#define B_N    4
#define NTOK   (B_N * S_LEN)     // 8192
#define VT     128               // vocab entries per tile
#define DT     32                // d rows per tile
#define NBIN   (VOCAB / VT)      // 250
#define NDT    (DMODEL / DT)     // 32
#define GRP    8                 // vocab tiles per block
#define NVG    ((NBIN + GRP - 1) / GRP)   // 32
#define NBLK   (NDT * NVG)       // 1024
#define LSTRIDE (VT + 1)         // 129: column reads 2-way only (free)

// ---- pass 1: bin tokens by vocab-tile (single block: hist+scan+scatter) ----
__global__ __launch_bounds__(1024) void bin_k(const int* __restrict__ text,
                                              int2* __restrict__ sorted,
                                              int* __restrict__ tile_off) {
    __shared__ int cnt[256];
    __shared__ int scn[256];
    const int t = threadIdx.x;
    if (t < 256) cnt[t] = 0;
    __syncthreads();

    int toks[8];
    #pragma unroll
    for (int j = 0; j < 8; ++j) {
        toks[j] = text[t * 8 + j];
        atomicAdd(&cnt[toks[j] >> 7], 1);
    }
    __syncthreads();

    if (t < 256) scn[t] = cnt[t];
    __syncthreads();
    for (int off = 1; off < 256; off <<= 1) {
        int x = 0;
        if (t < 256 && t >= off) x = scn[t - off];
        __syncthreads();
        if (t < 256) scn[t] += x;
        __syncthreads();
    }
    if (t < 256) {
        const int start = scn[t] - cnt[t];   // exclusive
        tile_off[t] = start;
        cnt[t] = start;                      // running cursor
    }
    __syncthreads();

    #pragma unroll
    for (int j = 0; j < 8; ++j) {
        const int tok = toks[j];
        const int slot = atomicAdd(&cnt[tok >> 7], 1);
        sorted[slot] = make_int2(tok, t * 8 + j);
    }
}

// ---- pass 2: pipelined coalesced W sweep, scatter-free gather ----
__global__ __launch_bounds__(256) void gather_k(const int2* __restrict__ sorted,
                                                const int* __restrict__ tile_off,
                                                const float* __restrict__ W,
                                                const float* __restrict__ bias,
                                                const float* __restrict__ pe,
                                                float* __restrict__ out) {
    __shared__ float lds[2][DT][LSTRIDE];    // 33 KB -> 4 blocks/CU

    const int bid = blockIdx.x;
    const int dt = bid & (NDT - 1);          // 0..31
    const int vg = bid >> 5;                 // 0..31
    const int d0 = dt * DT;
    const int t  = threadIdx.x;

    // staging lane assignment: 128-float row piece per 32 threads
    const int c4 = t & 31;                   // float4 column 0..31
    const int r0 = t >> 5;                   // row 0..7 (stride 8)

    // processing lane assignment
    const int lane = t & 63;
    const int wv   = t >> 6;                 // wave 0..3
    const int half = lane >> 5;              // 0/1: two tokens per wave-iter
    const int dl   = lane & 31;              // d within tile
    const float bv = bias[d0 + dl];

    const int vt_begin = vg * GRP;
    const int vt_end   = (vt_begin + GRP < NBIN) ? vt_begin + GRP : NBIN;
    const int ntile    = vt_end - vt_begin;

    float4 r[4];

    // stage tile vt into registers (4 coalesced float4 loads, independent)
    auto stage_regs = [&](int vt) {
        const float* wp = W + (size_t)(d0 + r0) * VOCAB + vt * VT + c4 * 4;
        #pragma unroll
        for (int i = 0; i < 4; ++i)
            r[i] = *reinterpret_cast<const float4*>(wp + (size_t)(8 * i) * VOCAB);
    };
    auto write_lds = [&](int buf) {
        #pragma unroll
        for (int i = 0; i < 4; ++i) {
            float* lp = &lds[buf][r0 + 8 * i][c4 * 4];
            lp[0] = r[i].x; lp[1] = r[i].y; lp[2] = r[i].z; lp[3] = r[i].w;
        }
    };

    stage_regs(vt_begin);
    write_lds(0);

    for (int g = 0; g < ntile; ++g) {
        if (g + 1 < ntile) stage_regs(vt_begin + g + 1);  // loads in flight
        __syncthreads();                                   // lds[g&1] ready

        const int vt = vt_begin + g;
        const int v0 = vt * VT;
        const int a0 = tile_off[vt];
        const int a1 = tile_off[vt + 1];
        const float* ldsb = &lds[g & 1][0][0];

        for (int i = a0 + wv * 2 + half; i < a1; i += 8) {
            const int2 p = sorted[i];        // half-wave-uniform broadcast
            const int tokl = p.x - v0;
            const int bs   = p.y;
            const int s    = bs & (S_LEN - 1);
            const float wval = ldsb[dl * LSTRIDE + tokl];  // 2-way bank only
            const float pv = pe[(size_t)s * DMODEL + d0 + dl];
            out[(size_t)bs * DMODEL + d0 + dl] = wval + bv + pv;
        }
        // write NEXT tile into the other buffer; readers of that buffer
        // finished before the barrier above. One barrier per tile total.
        if (g + 1 < ntile) write_lds((g + 1) & 1);
    }
}

// ---- fallback (ws too small): direct gather ----
__global__ __launch_bounds__(256) void embed_pe_direct(const int* __restrict__ text,
                                                       const float* __restrict__ W,
                                                       const float* __restrict__ bias,
                                                       const float* __restrict__ pe,
                                                       float* __restrict__ out) {
    const int bs = blockIdx.x;
    const int s  = bs & (S_LEN - 1);
    const int tok = text[bs];
    const int d = threadIdx.x << 2;
    const float4 b4 = *reinterpret_cast<const float4*>(bias + d);
    const float4 p4 = *reinterpret_cast<const float4*>(pe + (size_t)s * DMODEL + d);
    const float* wcol = W + (size_t)d * VOCAB + tok;
    float4 o;
    o.x = wcol[0]                 + b4.x + p4.x;
    o.y = wcol[(size_t)VOCAB]     + b4.y + p4.y;
    o.z = wcol[(size_t)2 * VOCAB] + b4.z + p4.z;
    o.w = wcol[(size_t)3 * VOCAB] + b4.w + p4.w;
    *reinterpret_cast<float4*>(out + (size_t)bs * DMODEL + d) = o;
}

extern "C" void kernel_launch(void* const* d_in, const int* in_sizes, int n_in,
                              void* d_out, int out_size, void* d_ws, size_t ws_size,
                              hipStream_t stream) {
    const int*   text = (const int*)d_in[0];
    const float* W    = (const float*)d_in[1];
    const float* bias = (const float*)d_in[2];
    const float* pe   = (const float*)d_in[3];
    float*       out  = (float*)d_out;

    const size_t sorted_bytes = (size_t)NTOK * sizeof(int2);   // 64 KB
    const size_t off_bytes    = 257 * sizeof(int);
    if (ws_size < sorted_bytes + off_bytes) {
        embed_pe_direct<<<NTOK, 256, 0, stream>>>(text, W, bias, pe, out);
        return;
    }

    int2* sorted   = (int2*)d_ws;
    int*  tile_off = (int*)((char*)d_ws + sorted_bytes);

    bin_k   <<<1, 1024, 0, stream>>>(text, sorted, tile_off);
    gather_k<<<NBLK, 256, 0, stream>>>(sorted, tile_off, W, bias, pe, out);
}

// Round 7
// 40.166 us; speedup vs baseline: 1.1251x; 1.1251x over previous
//
#include <hip/hip_runtime.h>

// out[b,s,:] = W[:, text[b,s]] + bias + pe[s,:]
// text: int32 [B,S]; W: f32 [D, VOCAB]; bias: f32 [D]; pe: f32 [MAX_LEN, D]
//
// Round 7: round-5 structure (proven 42.7us; round-6 in-block pipelining
// regressed) with halved LDS tile: VT=64 -> 16.6 KB/block -> 8 blocks/CU =
// 32 waves/CU (was 4 blocks/16 waves). One-shot stage->barrier->process
// blocks; occupancy (not explicit pipelining) hides the phase stalls.

#define VOCAB  32000
#define DMODEL 1024
#define S_LEN  2048
#define B_N    4
#define NTOK   (B_N * S_LEN)     // 8192
#define VT     64                // vocab entries per tile
#define DT     64                // d rows per tile
#define NBIN   (VOCAB / VT)      // 500
#define NDT    (DMODEL / DT)     // 16
#define NBLK   (NBIN * NDT)      // 8000
#define LSTRIDE (VT + 1)         // 65: column reads 2-way only (free)

// ---- pass 1: bin tokens by 64-wide vocab tile (single block) ----
__global__ __launch_bounds__(1024) void bin_k(const int* __restrict__ text,
                                              int2* __restrict__ sorted,
                                              int* __restrict__ tile_off) {
    __shared__ int cnt[512];
    __shared__ int scn[512];
    const int t = threadIdx.x;
    if (t < 512) cnt[t] = 0;
    __syncthreads();

    int toks[8];
    #pragma unroll
    for (int j = 0; j < 8; ++j) {
        toks[j] = text[t * 8 + j];
        atomicAdd(&cnt[toks[j] >> 6], 1);
    }
    __syncthreads();

    if (t < 512) scn[t] = cnt[t];
    __syncthreads();
    for (int off = 1; off < 512; off <<= 1) {
        int x = 0;
        if (t < 512 && t >= off) x = scn[t - off];
        __syncthreads();
        if (t < 512) scn[t] += x;
        __syncthreads();
    }
    if (t < 512) {
        const int start = scn[t] - cnt[t];   // exclusive
        tile_off[t] = start;                 // tile_off[500] = 8192
        cnt[t] = start;                      // running cursor
    }
    __syncthreads();

    #pragma unroll
    for (int j = 0; j < 8; ++j) {
        const int tok = toks[j];
        const int slot = atomicAdd(&cnt[tok >> 6], 1);
        sorted[slot] = make_int2(tok, t * 8 + j);
    }
}

// ---- pass 2: coalesced W sweep, LDS-staged scatter-free gather ----
__global__ __launch_bounds__(256, 8) void gather_k(const int2* __restrict__ sorted,
                                                   const int* __restrict__ tile_off,
                                                   const float* __restrict__ W,
                                                   const float* __restrict__ bias,
                                                   const float* __restrict__ pe,
                                                   float* __restrict__ out) {
    __shared__ float lds[DT * LSTRIDE];      // 16.6 KB -> 8 blocks/CU

    const int bid = blockIdx.x;
    const int vt = bid >> 4;                 // 0..499
    const int dt = bid & (NDT - 1);          // 0..15  (dt%8 -> XCD: pe L2-local)
    const int v0 = vt * VT;
    const int d0 = dt * DT;
    const int t  = threadIdx.x;

    // stage W[d0:d0+64][v0:v0+64] into LDS, coalesced float4 reads
    {
        const int c4 = t & 15;               // float4 column 0..15
        const int r0 = t >> 4;               // row 0..15
        #pragma unroll
        for (int i = 0; i < 4; ++i) {
            const int row = r0 + i * 16;
            const float4 w4 = *reinterpret_cast<const float4*>(
                W + (size_t)(d0 + row) * VOCAB + v0 + c4 * 4);
            float* lp = lds + row * LSTRIDE + c4 * 4;
            lp[0] = w4.x; lp[1] = w4.y; lp[2] = w4.z; lp[3] = w4.w;
        }
    }
    __syncthreads();

    const int a0 = tile_off[vt];
    const int a1 = tile_off[vt + 1];
    const int lane = t & 63;
    const int wv   = t >> 6;                 // 4 tokens in parallel
    const float bv = bias[d0 + lane];

    for (int i = a0 + wv; i < a1; i += 4) {
        const int2 p = sorted[i];            // wave-uniform broadcast
        const int tokl = p.x - v0;
        const int bs   = p.y;
        const int s    = bs & (S_LEN - 1);
        const float wval = lds[lane * LSTRIDE + tokl];   // (lane+tokl)%32: 2-way
        const float pv = pe[(size_t)s * DMODEL + d0 + lane];
        out[(size_t)bs * DMODEL + d0 + lane] = wval + bv + pv;
    }
}

// ---- fallback (ws too small): direct gather ----
__global__ __launch_bounds__(256) void embed_pe_direct(const int* __restrict__ text,
                                                       const float* __restrict__ W,
                                                       const float* __restrict__ bias,
                                                       const float* __restrict__ pe,
                                                       float* __restrict__ out) {
    const int bs = blockIdx.x;
    const int s  = bs & (S_LEN - 1);
    const int tok = text[bs];
    const int d = threadIdx.x << 2;
    const float4 b4 = *reinterpret_cast<const float4*>(bias + d);
    const float4 p4 = *reinterpret_cast<const float4*>(pe + (size_t)s * DMODEL + d);
    const float* wcol = W + (size_t)d * VOCAB + tok;
    float4 o;
    o.x = wcol[0]                 + b4.x + p4.x;
    o.y = wcol[(size_t)VOCAB]     + b4.y + p4.y;
    o.z = wcol[(size_t)2 * VOCAB] + b4.z + p4.z;
    o.w = wcol[(size_t)3 * VOCAB] + b4.w + p4.w;
    *reinterpret_cast<float4*>(out + (size_t)bs * DMODEL + d) = o;
}

extern "C" void kernel_launch(void* const* d_in, const int* in_sizes, int n_in,
                              void* d_out, int out_size, void* d_ws, size_t ws_size,
                              hipStream_t stream) {
    const int*   text = (const int*)d_in[0];
    const float* W    = (const float*)d_in[1];
    const float* bias = (const float*)d_in[2];
    const float* pe   = (const float*)d_in[3];
    float*       out  = (float*)d_out;

    const size_t sorted_bytes = (size_t)NTOK * sizeof(int2);   // 64 KB
    const size_t off_bytes    = 513 * sizeof(int);
    if (ws_size < sorted_bytes + off_bytes) {
        embed_pe_direct<<<NTOK, 256, 0, stream>>>(text, W, bias, pe, out);
        return;
    }

    int2* sorted   = (int2*)d_ws;
    int*  tile_off = (int*)((char*)d_ws + sorted_bytes);

    bin_k   <<<1, 1024, 0, stream>>>(text, sorted, tile_off);
    gather_k<<<NBLK, 256, 0, stream>>>(sorted, tile_off, W, bias, pe, out);
}